// Round 6
// baseline (461.287 us; speedup 1.0000x reference)
//
#include <hip/hip_runtime.h>

#define HH 256       // hidden size
#define NB 64        // batch (segments)
#define ROWS 64      // rows per block tile
#define NTOT 262144  // NK == NC
#define THREADS 256  // 4 waves

typedef _Float16 half8 __attribute__((ext_vector_type(8)));
typedef _Float16 half4 __attribute__((ext_vector_type(4)));
typedef float f32x4 __attribute__((ext_vector_type(4)));

// act LDS tile: [row][k] fp16, 64 rows x 256 k = 32KB, row stride 512B.
// XOR swizzle: reduces stride-512B row aliasing to 2-way (measured ~2.5% cost).
__device__ __forceinline__ uint32_t swz(uint32_t r, uint32_t k) {
  return (((r << 9) + (k << 1)) ^ ((r & 7) << 4)) ^ ((r & 8) << 3);
}

// ---------------------------------------------------------------------------
// Heavy layer via MFMA, swapped operands:
//   D[m=j][n=r] = sum_k WT[j][k] * act[r][k]
// A-frag (weights): lane l -> WT[j0+jf*16+(l&15)][ks*32+(l>>4)*8 .. +8] (16B L2)
// B-frag (act):     lane l -> act[rf*16+(l&15)][ks*32+(l>>4)*8 .. +8]   (16B LDS)
// D-frag: r = l&15, j = (l>>4)*4 + reg -> 4 consecutive j per lane -> 8B write.
// Wave tile: 64r x 64j (j0 = wid*64) -> weight matrix read exactly once/block.
// ks loop FULLY unrolled: low live-set (acc64 + b16 + a4) gives LLVM headroom
// to software-pipeline the global A-loads / LDS B-reads across ks steps.
// MODE: 0 = relu; 1 = plain (trunk c); 2 = multiply seg_mean[seg_g[r]] (branch)
// ---------------------------------------------------------------------------
template<int MODE>
__device__ __forceinline__ void heavy_layer(char* act, const _Float16* __restrict__ WT,
                                            const float* __restrict__ bias,
                                            const float* __restrict__ seg_mean,
                                            const int* __restrict__ seg_g, int tid)
{
  const int wid  = tid >> 6;
  const int lane = tid & 63;
  const int lr   = lane & 15;
  const int lg   = lane >> 4;
  const int j0   = wid << 6;

  f32x4 acc[4][4];  // [jf][rf]
#pragma unroll
  for (int jf = 0; jf < 4; ++jf)
#pragma unroll
    for (int rf = 0; rf < 4; ++rf)
      acc[jf][rf] = (f32x4){0.f, 0.f, 0.f, 0.f};

  const _Float16* wbase = WT + (j0 + lr) * HH + lg * 8;

#pragma unroll
  for (int ks = 0; ks < 8; ++ks) {
    half8 b[4];
#pragma unroll
    for (int rf = 0; rf < 4; ++rf)
      b[rf] = *(const half8*)(act + swz(rf * 16 + lr, ks * 32 + lg * 8));
#pragma unroll
    for (int jf = 0; jf < 4; ++jf) {
      half8 a = *(const half8*)(wbase + jf * 16 * HH + ks * 32);
#pragma unroll
      for (int rf = 0; rf < 4; ++rf)
        acc[jf][rf] = __builtin_amdgcn_mfma_f32_16x16x32_f16(a, b[rf], acc[jf][rf], 0, 0, 0);
    }
  }

  __syncthreads();  // all waves done READING act before overwrite

  int sseg[4];
  if (MODE == 2) {
#pragma unroll
    for (int rf = 0; rf < 4; ++rf) sseg[rf] = seg_g[rf * 16 + lr];
  }

#pragma unroll
  for (int jf = 0; jf < 4; ++jf) {
    f32x4 bj = *(const f32x4*)(bias + j0 + jf * 16 + lg * 4);
#pragma unroll
    for (int rf = 0; rf < 4; ++rf) {
      f32x4 v = acc[jf][rf] + bj;
      if (MODE == 2) {
        f32x4 sm = *(const f32x4*)(seg_mean + sseg[rf] * HH + j0 + jf * 16 + lg * 4);
        v *= sm;
      }
      half4 h;
#pragma unroll
      for (int u = 0; u < 4; ++u) {
        float x = v[u];
        if (MODE == 0) x = fmaxf(x, 0.f);
        h[u] = (_Float16)x;
      }
      *(half4*)(act + swz(rf * 16 + lr, j0 + jf * 16 + lg * 4)) = h;
    }
  }
  __syncthreads();
}

// layer 1 via MFMA: F=3 -> H (relu), K padded 3 -> 32 with zeros.
// x read directly from global (lg==0 lanes, L1-cached), no LDS staging.
__device__ __forceinline__ void layer1_mfma(char* act, const float* __restrict__ x,
                                            int r0g, const float* __restrict__ W0,
                                            const float* __restrict__ b0, int tid)
{
  const int wid  = tid >> 6;
  const int lane = tid & 63;
  const int lr   = lane & 15;
  const int lg   = lane >> 4;
  const int j0   = wid << 6;

  half8 a[4], b[4];
#pragma unroll
  for (int jf = 0; jf < 4; ++jf) {
    half8 v = {0, 0, 0, 0, 0, 0, 0, 0};
    if (lg == 0) {
      int j = j0 + jf * 16 + lr;
      v[0] = (_Float16)W0[j];
      v[1] = (_Float16)W0[HH + j];
      v[2] = (_Float16)W0[2 * HH + j];
    }
    a[jf] = v;
  }
#pragma unroll
  for (int rf = 0; rf < 4; ++rf) {
    half8 v = {0, 0, 0, 0, 0, 0, 0, 0};
    if (lg == 0) {
      const float* xp = x + (size_t)(r0g + rf * 16 + lr) * 3;
      v[0] = (_Float16)xp[0];
      v[1] = (_Float16)xp[1];
      v[2] = (_Float16)xp[2];
    }
    b[rf] = v;
  }

  f32x4 acc[4][4];
#pragma unroll
  for (int jf = 0; jf < 4; ++jf)
#pragma unroll
    for (int rf = 0; rf < 4; ++rf)
      acc[jf][rf] = (f32x4){0.f, 0.f, 0.f, 0.f};
#pragma unroll
  for (int jf = 0; jf < 4; ++jf)
#pragma unroll
    for (int rf = 0; rf < 4; ++rf)
      acc[jf][rf] = __builtin_amdgcn_mfma_f32_16x16x32_f16(a[jf], b[rf], acc[jf][rf], 0, 0, 0);

#pragma unroll
  for (int jf = 0; jf < 4; ++jf) {
    f32x4 bj = *(const f32x4*)(b0 + j0 + jf * 16 + lg * 4);
#pragma unroll
    for (int rf = 0; rf < 4; ++rf) {
      f32x4 v = acc[jf][rf] + bj;
      half4 h;
#pragma unroll
      for (int u = 0; u < 4; ++u)
        h[u] = (_Float16)fmaxf(v[u], 0.f);
      *(half4*)(act + swz(rf * 16 + lr, j0 + jf * 16 + lg * 4)) = h;
    }
  }
  __syncthreads();
}

// ---------------------------------------------------------------------------
__global__ __launch_bounds__(THREADS, 4)
void trunk_kernel(const float* __restrict__ nodes, const int* __restrict__ coord_seg,
                  const float* __restrict__ tw0, const float* __restrict__ tb0,
                  const _Float16* __restrict__ wt1, const float* __restrict__ tb1,
                  const _Float16* __restrict__ wt2, const float* __restrict__ tb2,
                  float* __restrict__ seg_sum)
{
  __shared__ __align__(16) char act[ROWS * HH * 2];  // 32KB
  const int tid = threadIdx.x;
  const int r0g = blockIdx.x * ROWS;

  layer1_mfma(act, nodes, r0g, tw0, tb0, tid);
  heavy_layer<0>(act, wt1, tb1, nullptr, nullptr, tid);
  heavy_layer<1>(act, wt2, tb2, nullptr, nullptr, tid);  // c (no relu)

  // per-segment sums of c; segs sorted -> ~98% of tiles are single-segment.
  {
    const int j = tid;
    const int s_lo = coord_seg[r0g];
    const int s_hi = coord_seg[r0g + ROWS - 1];
    if (s_lo == s_hi) {
      float p = 0.f;
#pragma unroll 8
      for (int r = 0; r < ROWS; ++r)
        p += (float)*(const _Float16*)(act + swz(r, j));
      atomicAdd(&seg_sum[s_lo * HH + j], p);
    } else {
      for (int s = s_lo; s <= s_hi; ++s) {
        float p = 0.f;
        for (int r = 0; r < ROWS; ++r)
          if (coord_seg[r0g + r] == s)
            p += (float)*(const _Float16*)(act + swz(r, j));
        atomicAdd(&seg_sum[s * HH + j], p);
      }
    }
  }
}

__global__ __launch_bounds__(THREADS, 4)
void branch_kernel(const float* __restrict__ known_nodes, const int* __restrict__ known_seg,
                   const float* __restrict__ bw0, const float* __restrict__ bb0,
                   const _Float16* __restrict__ wt1, const float* __restrict__ bb1,
                   const _Float16* __restrict__ wt2, const float* __restrict__ bb2,
                   const float* __restrict__ seg_mean,
                   const _Float16* __restrict__ wto, const float* __restrict__ ob0,
                   const float* __restrict__ ow1, const float* __restrict__ ob1,
                   float* __restrict__ out)
{
  __shared__ __align__(16) char act[ROWS * HH * 2];  // 32KB
  __shared__ float ps[4 * ROWS * 3];                 // tail partials, 3KB
  const int tid = threadIdx.x;
  const int r0g = blockIdx.x * ROWS;

  layer1_mfma(act, known_nodes, r0g, bw0, bb0, tid);
  heavy_layer<0>(act, wt1, bb1, nullptr, nullptr, tid);
  heavy_layer<2>(act, wt2, bb2, seg_mean, known_seg + r0g, tid);  // f*seg_mean
  heavy_layer<0>(act, wto, ob0, nullptr, nullptr, tid);           // relu(.@ow0+ob0)

  // out = h @ ow1 + ob1 (256 -> 3): all 256 threads, 4 k-quarters in parallel
  {
    const int r = tid & 63;
    const int q = tid >> 6;
    float o0 = 0.f, o1 = 0.f, o2 = 0.f;
    for (int kk = 0; kk < 64; kk += 8) {
      int k0 = q * 64 + kk;
      half8 h = *(const half8*)(act + swz(r, k0));
#pragma unroll
      for (int u = 0; u < 8; ++u) {
        float a = (float)h[u];
        o0 = fmaf(a, ow1[(k0 + u) * 3 + 0], o0);
        o1 = fmaf(a, ow1[(k0 + u) * 3 + 1], o1);
        o2 = fmaf(a, ow1[(k0 + u) * 3 + 2], o2);
      }
    }
    float* p = ps + q * ROWS * 3;
    p[r * 3 + 0] = o0; p[r * 3 + 1] = o1; p[r * 3 + 2] = o2;
  }
  __syncthreads();
  if (tid < ROWS) {
    const int r = tid;
    float* dst = out + (size_t)(r0g + r) * 3;
#pragma unroll
    for (int c = 0; c < 3; ++c) {
      float o = ob1[c];
#pragma unroll
      for (int q = 0; q < 4; ++q) o += ps[q * ROWS * 3 + r * 3 + c];
      dst[c] = o;
    }
  }
}

// W[256][256] fp32 row-major -> WT[j][k] fp16 (5 matrices), once per launch.
struct WPtrs { const float* w[5]; _Float16* wt[5]; };
__global__ void transpose_kernel(WPtrs p)
{
  const int m = blockIdx.x >> 8;   // matrix
  const int j = blockIdx.x & 255;  // output row
  const int k = threadIdx.x;       // 256 threads, coalesced writes
  p.wt[m][j * HH + k] = (_Float16)p.w[m][k * HH + j];
}

__global__ void zero_kernel(float* __restrict__ p, int n)
{
  int i = blockIdx.x * blockDim.x + threadIdx.x;
  if (i < n) p[i] = 0.f;
}

__global__ void mean_kernel(const float* __restrict__ seg_sum,
                            const int* __restrict__ coord_seg,
                            float* __restrict__ seg_mean)
{
  const int b = blockIdx.x;
  int lo = 0, n = NTOT;
  while (n > 0) { int h = n >> 1; int mid = lo + h;
    if (coord_seg[mid] < b) { lo = mid + 1; n -= h + 1; } else n = h; }
  int hi = lo; n = NTOT - lo;
  while (n > 0) { int h = n >> 1; int mid = hi + h;
    if (coord_seg[mid] < b + 1) { hi = mid + 1; n -= h + 1; } else n = h; }
  float inv = 1.0f / fmaxf((float)(hi - lo), 1.0f);
  seg_mean[b * HH + threadIdx.x] = seg_sum[b * HH + threadIdx.x] * inv;
}

// ---------------------------------------------------------------------------
extern "C" void kernel_launch(void* const* d_in, const int* in_sizes, int n_in,
                              void* d_out, int out_size, void* d_ws, size_t ws_size,
                              hipStream_t stream)
{
  const float* known_nodes = (const float*)d_in[0];
  const float* nodes       = (const float*)d_in[1];
  const int*   known_seg   = (const int*)d_in[2];
  const int*   coord_seg   = (const int*)d_in[3];
  const float* bw0 = (const float*)d_in[4];
  const float* bb0 = (const float*)d_in[5];
  const float* bw1 = (const float*)d_in[6];
  const float* bb1 = (const float*)d_in[7];
  const float* bw2 = (const float*)d_in[8];
  const float* bb2 = (const float*)d_in[9];
  const float* tw0 = (const float*)d_in[10];
  const float* tb0 = (const float*)d_in[11];
  const float* tw1 = (const float*)d_in[12];
  const float* tb1 = (const float*)d_in[13];
  const float* tw2 = (const float*)d_in[14];
  const float* tb2 = (const float*)d_in[15];
  const float* ow0 = (const float*)d_in[16];
  const float* ob0 = (const float*)d_in[17];
  const float* ow1 = (const float*)d_in[18];
  const float* ob1 = (const float*)d_in[19];

  float* out      = (float*)d_out;
  float* seg_sum  = (float*)d_ws;                        // [64][256] f32
  float* seg_mean = seg_sum + NB * HH;                   // [64][256] f32
  _Float16* wtb   = (_Float16*)((char*)d_ws + (size_t)2 * NB * HH * 4);
  _Float16* wt_tw1 = wtb + 0 * HH * HH;
  _Float16* wt_tw2 = wtb + 1 * HH * HH;
  _Float16* wt_bw1 = wtb + 2 * HH * HH;
  _Float16* wt_bw2 = wtb + 3 * HH * HH;
  _Float16* wt_ow0 = wtb + 4 * HH * HH;

  WPtrs wp;
  wp.w[0] = tw1; wp.wt[0] = wt_tw1;
  wp.w[1] = tw2; wp.wt[1] = wt_tw2;
  wp.w[2] = bw1; wp.wt[2] = wt_bw1;
  wp.w[3] = bw2; wp.wt[3] = wt_bw2;
  wp.w[4] = ow0; wp.wt[4] = wt_ow0;

  transpose_kernel<<<5 * 256, 256, 0, stream>>>(wp);
  zero_kernel<<<(NB * HH + 255) / 256, 256, 0, stream>>>(seg_sum, NB * HH);
  trunk_kernel<<<NTOT / ROWS, THREADS, 0, stream>>>(nodes, coord_seg,
                                                    tw0, tb0, wt_tw1, tb1, wt_tw2, tb2,
                                                    seg_sum);
  mean_kernel<<<NB, 256, 0, stream>>>(seg_sum, coord_seg, seg_mean);
  branch_kernel<<<NTOT / ROWS, THREADS, 0, stream>>>(known_nodes, known_seg,
                                                     bw0, bb0, wt_bw1, bb1, wt_bw2, bb2,
                                                     seg_mean,
                                                     wt_ow0, ob0, ow1, ob1,
                                                     out);
}

// Round 7
// 280.804 us; speedup vs baseline: 1.6427x; 1.6427x over previous
//
#include <hip/hip_runtime.h>

#define HH 256       // hidden size
#define NB 64        // batch (segments)
#define ROWS 128     // rows per block tile
#define NTOT 262144  // NK == NC
#define THREADS 256  // 4 waves

typedef _Float16 half8 __attribute__((ext_vector_type(8)));
typedef _Float16 half4 __attribute__((ext_vector_type(4)));
typedef float f32x4 __attribute__((ext_vector_type(4)));

// act LDS tile: [row][k] fp16, 128 rows x 256 k = 64KB, row stride 512B.
// XOR swizzle: reduces stride-512B row aliasing to 2-way.
__device__ __forceinline__ uint32_t swz(uint32_t r, uint32_t k) {
  return (((r << 9) + (k << 1)) ^ ((r & 7) << 4)) ^ ((r & 8) << 3);
}

// ---------------------------------------------------------------------------
// Heavy layer via MFMA, swapped operands: D[j][r] = sum_k WT[j][k]*act[r][k]
// Wave tile: 128r x 64j, j0 = wid*64 -> the block reads W exactly ONCE per
// layer (j-slices disjoint) = 128KB L2/layer/block; B-LDS = 256KB/layer/block.
// R4-proven loop shape: unroll 2, ONE a-frag live at a time (no spill).
// MODE: 0 = relu; 1 = plain (trunk c); 2 = multiply seg_mean[seg_g[r]] (branch)
// ---------------------------------------------------------------------------
template<int MODE>
__device__ __forceinline__ void heavy_layer(char* act, const _Float16* __restrict__ WT,
                                            const float* __restrict__ bias,
                                            const float* __restrict__ seg_mean,
                                            const int* __restrict__ seg_g, int tid)
{
  const int wid  = tid >> 6;
  const int lane = tid & 63;
  const int lr   = lane & 15;
  const int lg   = lane >> 4;
  const int j0   = wid << 6;

  f32x4 acc[4][8];  // [jf][rf] = 128 VGPRs
#pragma unroll
  for (int jf = 0; jf < 4; ++jf)
#pragma unroll
    for (int rf = 0; rf < 8; ++rf)
      acc[jf][rf] = (f32x4){0.f, 0.f, 0.f, 0.f};

  const _Float16* wbase = WT + (j0 + lr) * HH + lg * 8;

#pragma unroll 2
  for (int ks = 0; ks < 8; ++ks) {
    half8 b[8];
#pragma unroll
    for (int rf = 0; rf < 8; ++rf)
      b[rf] = *(const half8*)(act + swz(rf * 16 + lr, ks * 32 + lg * 8));
#pragma unroll
    for (int jf = 0; jf < 4; ++jf) {
      half8 a = *(const half8*)(wbase + jf * 16 * HH + ks * 32);
#pragma unroll
      for (int rf = 0; rf < 8; ++rf)
        acc[jf][rf] = __builtin_amdgcn_mfma_f32_16x16x32_f16(a, b[rf], acc[jf][rf], 0, 0, 0);
    }
  }

  __syncthreads();  // all waves done READING act before overwrite

  int sseg[8];
  if (MODE == 2) {
#pragma unroll
    for (int rf = 0; rf < 8; ++rf) sseg[rf] = seg_g[rf * 16 + lr];
  }

#pragma unroll
  for (int jf = 0; jf < 4; ++jf) {
    f32x4 bj = *(const f32x4*)(bias + j0 + jf * 16 + lg * 4);
#pragma unroll
    for (int rf = 0; rf < 8; ++rf) {
      f32x4 v = acc[jf][rf] + bj;
      if (MODE == 2) {
        f32x4 sm = *(const f32x4*)(seg_mean + sseg[rf] * HH + j0 + jf * 16 + lg * 4);
        v *= sm;
      }
      half4 h;
#pragma unroll
      for (int u = 0; u < 4; ++u) {
        float x = v[u];
        if (MODE == 0) x = fmaxf(x, 0.f);
        h[u] = (_Float16)x;
      }
      *(half4*)(act + swz(rf * 16 + lr, j0 + jf * 16 + lg * 4)) = h;
    }
  }
  __syncthreads();
}

// layer 1 via MFMA: F=3 -> H (relu), K padded 3 -> 32 with zeros.
// x read directly from global (lg==0 lanes, L1-cached).
__device__ __forceinline__ void layer1_mfma(char* act, const float* __restrict__ x,
                                            int r0g, const float* __restrict__ W0,
                                            const float* __restrict__ b0, int tid)
{
  const int wid  = tid >> 6;
  const int lane = tid & 63;
  const int lr   = lane & 15;
  const int lg   = lane >> 4;
  const int j0   = wid << 6;

  half8 a[4];
#pragma unroll
  for (int jf = 0; jf < 4; ++jf) {
    half8 v = {0, 0, 0, 0, 0, 0, 0, 0};
    if (lg == 0) {
      int j = j0 + jf * 16 + lr;
      v[0] = (_Float16)W0[j];
      v[1] = (_Float16)W0[HH + j];
      v[2] = (_Float16)W0[2 * HH + j];
    }
    a[jf] = v;
  }

  f32x4 acc[4][8];
#pragma unroll
  for (int jf = 0; jf < 4; ++jf)
#pragma unroll
    for (int rf = 0; rf < 8; ++rf)
      acc[jf][rf] = (f32x4){0.f, 0.f, 0.f, 0.f};

#pragma unroll
  for (int rf = 0; rf < 8; ++rf) {
    half8 b = {0, 0, 0, 0, 0, 0, 0, 0};
    if (lg == 0) {
      const float* xp = x + (size_t)(r0g + rf * 16 + lr) * 3;
      b[0] = (_Float16)xp[0];
      b[1] = (_Float16)xp[1];
      b[2] = (_Float16)xp[2];
    }
#pragma unroll
    for (int jf = 0; jf < 4; ++jf)
      acc[jf][rf] = __builtin_amdgcn_mfma_f32_16x16x32_f16(a[jf], b, acc[jf][rf], 0, 0, 0);
  }

#pragma unroll
  for (int jf = 0; jf < 4; ++jf) {
    f32x4 bj = *(const f32x4*)(b0 + j0 + jf * 16 + lg * 4);
#pragma unroll
    for (int rf = 0; rf < 8; ++rf) {
      f32x4 v = acc[jf][rf] + bj;
      half4 h;
#pragma unroll
      for (int u = 0; u < 4; ++u)
        h[u] = (_Float16)fmaxf(v[u], 0.f);
      *(half4*)(act + swz(rf * 16 + lr, j0 + jf * 16 + lg * 4)) = h;
    }
  }
  __syncthreads();
}

// ---------------------------------------------------------------------------
__global__ __launch_bounds__(THREADS, 2)
void trunk_kernel(const float* __restrict__ nodes, const int* __restrict__ coord_seg,
                  const float* __restrict__ tw0, const float* __restrict__ tb0,
                  const _Float16* __restrict__ wt1, const float* __restrict__ tb1,
                  const _Float16* __restrict__ wt2, const float* __restrict__ tb2,
                  float* __restrict__ seg_sum)
{
  __shared__ __align__(16) char act[ROWS * HH * 2];  // 64KB
  const int tid = threadIdx.x;
  const int r0g = blockIdx.x * ROWS;

  layer1_mfma(act, nodes, r0g, tw0, tb0, tid);
  heavy_layer<0>(act, wt1, tb1, nullptr, nullptr, tid);
  heavy_layer<1>(act, wt2, tb2, nullptr, nullptr, tid);  // c (no relu)

  // per-segment sums of c; segs sorted -> most tiles single-segment.
  {
    const int j = tid;
    const int s_lo = coord_seg[r0g];
    const int s_hi = coord_seg[r0g + ROWS - 1];
    if (s_lo == s_hi) {
      float p = 0.f;
#pragma unroll 8
      for (int r = 0; r < ROWS; ++r)
        p += (float)*(const _Float16*)(act + swz(r, j));
      atomicAdd(&seg_sum[s_lo * HH + j], p);
    } else {
      for (int s = s_lo; s <= s_hi; ++s) {
        float p = 0.f;
        for (int r = 0; r < ROWS; ++r)
          if (coord_seg[r0g + r] == s)
            p += (float)*(const _Float16*)(act + swz(r, j));
        atomicAdd(&seg_sum[s * HH + j], p);
      }
    }
  }
}

__global__ __launch_bounds__(THREADS, 2)
void branch_kernel(const float* __restrict__ known_nodes, const int* __restrict__ known_seg,
                   const float* __restrict__ bw0, const float* __restrict__ bb0,
                   const _Float16* __restrict__ wt1, const float* __restrict__ bb1,
                   const _Float16* __restrict__ wt2, const float* __restrict__ bb2,
                   const float* __restrict__ seg_mean,
                   const _Float16* __restrict__ wto, const float* __restrict__ ob0,
                   const float* __restrict__ ow1, const float* __restrict__ ob1,
                   float* __restrict__ out)
{
  __shared__ __align__(16) char act[ROWS * HH * 2];  // 64KB
  __shared__ float ps[2 * ROWS * 3];                 // tail partials, 3KB
  const int tid = threadIdx.x;
  const int r0g = blockIdx.x * ROWS;

  layer1_mfma(act, known_nodes, r0g, bw0, bb0, tid);
  heavy_layer<0>(act, wt1, bb1, nullptr, nullptr, tid);
  heavy_layer<2>(act, wt2, bb2, seg_mean, known_seg + r0g, tid);  // f*seg_mean
  heavy_layer<0>(act, wto, ob0, nullptr, nullptr, tid);           // relu(.@ow0+ob0)

  // out = h @ ow1 + ob1 (256 -> 3): 256 threads, 2 k-halves in parallel
  {
    const int r = tid & 127;
    const int q = tid >> 7;
    float o0 = 0.f, o1 = 0.f, o2 = 0.f;
    for (int kk = 0; kk < 128; kk += 8) {
      int k0 = q * 128 + kk;
      half8 h = *(const half8*)(act + swz(r, k0));
#pragma unroll
      for (int u = 0; u < 8; ++u) {
        float a = (float)h[u];
        o0 = fmaf(a, ow1[(k0 + u) * 3 + 0], o0);
        o1 = fmaf(a, ow1[(k0 + u) * 3 + 1], o1);
        o2 = fmaf(a, ow1[(k0 + u) * 3 + 2], o2);
      }
    }
    float* p = ps + q * ROWS * 3;
    p[r * 3 + 0] = o0; p[r * 3 + 1] = o1; p[r * 3 + 2] = o2;
  }
  __syncthreads();
  if (tid < ROWS) {
    const int r = tid;
    float* dst = out + (size_t)(r0g + r) * 3;
#pragma unroll
    for (int c = 0; c < 3; ++c)
      dst[c] = ob1[c] + ps[r * 3 + c] + ps[ROWS * 3 + r * 3 + c];
  }
}

// W[256][256] fp32 row-major -> WT[j][k] fp16 (5 matrices), once per launch.
struct WPtrs { const float* w[5]; _Float16* wt[5]; };
__global__ void transpose_kernel(WPtrs p)
{
  const int m = blockIdx.x >> 8;   // matrix
  const int j = blockIdx.x & 255;  // output row
  const int k = threadIdx.x;       // 256 threads, coalesced writes
  p.wt[m][j * HH + k] = (_Float16)p.w[m][k * HH + j];
}

__global__ void zero_kernel(float* __restrict__ p, int n)
{
  int i = blockIdx.x * blockDim.x + threadIdx.x;
  if (i < n) p[i] = 0.f;
}

__global__ void mean_kernel(const float* __restrict__ seg_sum,
                            const int* __restrict__ coord_seg,
                            float* __restrict__ seg_mean)
{
  const int b = blockIdx.x;
  int lo = 0, n = NTOT;
  while (n > 0) { int h = n >> 1; int mid = lo + h;
    if (coord_seg[mid] < b) { lo = mid + 1; n -= h + 1; } else n = h; }
  int hi = lo; n = NTOT - lo;
  while (n > 0) { int h = n >> 1; int mid = hi + h;
    if (coord_seg[mid] < b + 1) { hi = mid + 1; n -= h + 1; } else n = h; }
  float inv = 1.0f / fmaxf((float)(hi - lo), 1.0f);
  seg_mean[b * HH + threadIdx.x] = seg_sum[b * HH + threadIdx.x] * inv;
}

// ---------------------------------------------------------------------------
extern "C" void kernel_launch(void* const* d_in, const int* in_sizes, int n_in,
                              void* d_out, int out_size, void* d_ws, size_t ws_size,
                              hipStream_t stream)
{
  const float* known_nodes = (const float*)d_in[0];
  const float* nodes       = (const float*)d_in[1];
  const int*   known_seg   = (const int*)d_in[2];
  const int*   coord_seg   = (const int*)d_in[3];
  const float* bw0 = (const float*)d_in[4];
  const float* bb0 = (const float*)d_in[5];
  const float* bw1 = (const float*)d_in[6];
  const float* bb1 = (const float*)d_in[7];
  const float* bw2 = (const float*)d_in[8];
  const float* bb2 = (const float*)d_in[9];
  const float* tw0 = (const float*)d_in[10];
  const float* tb0 = (const float*)d_in[11];
  const float* tw1 = (const float*)d_in[12];
  const float* tb1 = (const float*)d_in[13];
  const float* tw2 = (const float*)d_in[14];
  const float* tb2 = (const float*)d_in[15];
  const float* ow0 = (const float*)d_in[16];
  const float* ob0 = (const float*)d_in[17];
  const float* ow1 = (const float*)d_in[18];
  const float* ob1 = (const float*)d_in[19];

  float* out      = (float*)d_out;
  float* seg_sum  = (float*)d_ws;                        // [64][256] f32
  float* seg_mean = seg_sum + NB * HH;                   // [64][256] f32
  _Float16* wtb   = (_Float16*)((char*)d_ws + (size_t)2 * NB * HH * 4);
  _Float16* wt_tw1 = wtb + 0 * HH * HH;
  _Float16* wt_tw2 = wtb + 1 * HH * HH;
  _Float16* wt_bw1 = wtb + 2 * HH * HH;
  _Float16* wt_bw2 = wtb + 3 * HH * HH;
  _Float16* wt_ow0 = wtb + 4 * HH * HH;

  WPtrs wp;
  wp.w[0] = tw1; wp.wt[0] = wt_tw1;
  wp.w[1] = tw2; wp.wt[1] = wt_tw2;
  wp.w[2] = bw1; wp.wt[2] = wt_bw1;
  wp.w[3] = bw2; wp.wt[3] = wt_bw2;
  wp.w[4] = ow0; wp.wt[4] = wt_ow0;

  transpose_kernel<<<5 * 256, 256, 0, stream>>>(wp);
  zero_kernel<<<(NB * HH + 255) / 256, 256, 0, stream>>>(seg_sum, NB * HH);
  trunk_kernel<<<NTOT / ROWS, THREADS, 0, stream>>>(nodes, coord_seg,
                                                    tw0, tb0, wt_tw1, tb1, wt_tw2, tb2,
                                                    seg_sum);
  mean_kernel<<<NB, 256, 0, stream>>>(seg_sum, coord_seg, seg_mean);
  branch_kernel<<<NTOT / ROWS, THREADS, 0, stream>>>(known_nodes, known_seg,
                                                     bw0, bb0, wt_bw1, bb1, wt_bw2, bb2,
                                                     seg_mean,
                                                     wt_ow0, ob0, ow1, ob1,
                                                     out);
}